// Round 1
// baseline (186.709 us; speedup 1.0000x reference)
//
#include <hip/hip_runtime.h>
#include <math.h>

// Channel-wise min/max over a [C, N] fp32 tensor.
// C = 1024, N = 32768 (derived at launch from in_sizes/out_size).
// Output layout: out[0..C) = min, out[C..2C) = max  (tuple concat order).

__global__ __launch_bounds__(256) void cw_minmax_kernel(
    const float* __restrict__ in, float* __restrict__ out, int nvec, int C) {
    const int c = blockIdx.x;
    const float4* __restrict__ row =
        reinterpret_cast<const float4*>(in) + (size_t)c * nvec;

    float vmin = INFINITY;
    float vmax = -INFINITY;

    // Grid-stride over the row's float4 elements: coalesced 16B/lane loads.
    for (int i = threadIdx.x; i < nvec; i += blockDim.x) {
        float4 v = row[i];
        vmin = fminf(vmin, fminf(fminf(v.x, v.y), fminf(v.z, v.w)));
        vmax = fmaxf(vmax, fmaxf(fmaxf(v.x, v.y), fmaxf(v.z, v.w)));
    }

    // Wave-64 butterfly reduction.
    #pragma unroll
    for (int off = 32; off > 0; off >>= 1) {
        vmin = fminf(vmin, __shfl_down(vmin, off, 64));
        vmax = fmaxf(vmax, __shfl_down(vmax, off, 64));
    }

    // Cross-wave merge via LDS (4 waves per 256-thread block).
    __shared__ float smin[4];
    __shared__ float smax[4];
    const int wave = threadIdx.x >> 6;
    const int lane = threadIdx.x & 63;
    if (lane == 0) { smin[wave] = vmin; smax[wave] = vmax; }
    __syncthreads();

    if (threadIdx.x == 0) {
        float m = smin[0], M = smax[0];
        #pragma unroll
        for (int w = 1; w < 4; ++w) {
            m = fminf(m, smin[w]);
            M = fmaxf(M, smax[w]);
        }
        out[c] = m;       // min_vals
        out[C + c] = M;   // max_vals
    }
}

extern "C" void kernel_launch(void* const* d_in, const int* in_sizes, int n_in,
                              void* d_out, int out_size, void* d_ws, size_t ws_size,
                              hipStream_t stream) {
    const float* in = (const float*)d_in[0];
    float* out = (float*)d_out;

    const int C = out_size / 2;             // 1024
    const int N = in_sizes[0] / C;          // 32768
    const int nvec = N / 4;                 // 8192 float4 per row

    cw_minmax_kernel<<<C, 256, 0, stream>>>(in, out, nvec, C);
}

// Round 2
// 183.997 us; speedup vs baseline: 1.0147x; 1.0147x over previous
//
#include <hip/hip_runtime.h>
#include <math.h>

// Channel-wise min/max over a [C, N] fp32 tensor.
// Output layout: out[0..C) = min, out[C..2C) = max (tuple concat order).
//
// Perf notes (R2): the R1 version was latency-bound (0.72 TB/s) because the
// grid-stride loop serialized to one outstanding load per wave. This version
// batches PER independent float4 loads into registers before reducing
// (8 KB in flight/wave) and uses 1024-thread blocks for ~full wave occupancy.

#define BS 1024  // threads per block (16 waves)

template <int PER>
__global__ __launch_bounds__(BS) void cw_minmax_spec(
    const float* __restrict__ in, float* __restrict__ out, int nvec, int C) {
    const int c = blockIdx.x;
    const float4* __restrict__ row =
        reinterpret_cast<const float4*>(in) + (size_t)c * nvec;

    // Batch all loads first: PER independent global_load_dwordx4 in flight.
    float4 v[PER];
    #pragma unroll
    for (int k = 0; k < PER; ++k)
        v[k] = row[threadIdx.x + k * BS];

    float vmin = INFINITY, vmax = -INFINITY;
    #pragma unroll
    for (int k = 0; k < PER; ++k) {
        vmin = fminf(vmin, fminf(fminf(v[k].x, v[k].y), fminf(v[k].z, v[k].w)));
        vmax = fmaxf(vmax, fmaxf(fmaxf(v[k].x, v[k].y), fmaxf(v[k].z, v[k].w)));
    }

    // Wave-64 butterfly reduction (xor: every lane ends with the result).
    #pragma unroll
    for (int off = 32; off > 0; off >>= 1) {
        vmin = fminf(vmin, __shfl_xor(vmin, off, 64));
        vmax = fmaxf(vmax, __shfl_xor(vmax, off, 64));
    }

    // Cross-wave merge via LDS (16 waves).
    __shared__ float smin[BS / 64];
    __shared__ float smax[BS / 64];
    const int wave = threadIdx.x >> 6;
    const int lane = threadIdx.x & 63;
    if (lane == 0) { smin[wave] = vmin; smax[wave] = vmax; }
    __syncthreads();

    if (threadIdx.x == 0) {
        float m = smin[0], M = smax[0];
        #pragma unroll
        for (int w = 1; w < BS / 64; ++w) {
            m = fminf(m, smin[w]);
            M = fmaxf(M, smax[w]);
        }
        out[c] = m;       // min_vals
        out[C + c] = M;   // max_vals
    }
}

// Generic fallback for shapes that don't divide evenly.
__global__ __launch_bounds__(256) void cw_minmax_generic(
    const float* __restrict__ in, float* __restrict__ out, int N, int C) {
    const int c = blockIdx.x;
    const float* __restrict__ row = in + (size_t)c * N;

    float vmin = INFINITY, vmax = -INFINITY;
    for (int i = threadIdx.x; i < N; i += blockDim.x) {
        float x = row[i];
        vmin = fminf(vmin, x);
        vmax = fmaxf(vmax, x);
    }
    #pragma unroll
    for (int off = 32; off > 0; off >>= 1) {
        vmin = fminf(vmin, __shfl_xor(vmin, off, 64));
        vmax = fmaxf(vmax, __shfl_xor(vmax, off, 64));
    }
    __shared__ float smin[4];
    __shared__ float smax[4];
    const int wave = threadIdx.x >> 6;
    const int lane = threadIdx.x & 63;
    if (lane == 0) { smin[wave] = vmin; smax[wave] = vmax; }
    __syncthreads();
    if (threadIdx.x == 0) {
        float m = smin[0], M = smax[0];
        for (int w = 1; w < 4; ++w) {
            m = fminf(m, smin[w]);
            M = fmaxf(M, smax[w]);
        }
        out[c] = m;
        out[C + c] = M;
    }
}

extern "C" void kernel_launch(void* const* d_in, const int* in_sizes, int n_in,
                              void* d_out, int out_size, void* d_ws, size_t ws_size,
                              hipStream_t stream) {
    const float* in = (const float*)d_in[0];
    float* out = (float*)d_out;

    const int C = out_size / 2;     // 1024
    const int N = in_sizes[0] / C;  // 32768

    if (N % (4 * BS) == 0) {
        const int nvec = N / 4;           // float4 per row
        const int per = nvec / BS;        // float4 per thread
        switch (per) {
            case 4:  cw_minmax_spec<4><<<C, BS, 0, stream>>>(in, out, nvec, C);  return;
            case 8:  cw_minmax_spec<8><<<C, BS, 0, stream>>>(in, out, nvec, C);  return;
            case 16: cw_minmax_spec<16><<<C, BS, 0, stream>>>(in, out, nvec, C); return;
            default: break;  // fall through to generic
        }
    }
    cw_minmax_generic<<<C, 256, 0, stream>>>(in, out, N, C);
}